// Round 2
// baseline (738.930 us; speedup 1.0000x reference)
//
#include <hip/hip_runtime.h>
#include <math.h>

#define N_NODES 50000
#define N_EDGES 800000
#define N_GRAPHS 512
#define IN_CH 7
#define HID 128
#define FC 128
#define ET (N_EDGES + N_NODES)   // real edges + self loops
#define NEG_SLOPE 0.2f

// ---------------- CSR build (once per call; edges identical across layers) ----------------

__global__ void k_init_deg(int* __restrict__ deg) {
  int i = blockIdx.x * blockDim.x + threadIdx.x;
  if (i < N_NODES) deg[i] = 1;  // self-loop contributes 1 incoming edge per node
}

__global__ void k_hist(const int* __restrict__ dst, int* __restrict__ deg) {
  int i = blockIdx.x * blockDim.x + threadIdx.x;
  if (i < N_EDGES) atomicAdd(&deg[dst[i]], 1);
}

// single-block hierarchical exclusive scan over N_NODES degrees
__global__ __launch_bounds__(1024) void k_scan(const int* __restrict__ deg,
                                               int* __restrict__ row_start,
                                               int* __restrict__ cursor) {
  __shared__ int wsum[16];
  __shared__ int s_carry;
  int tid = threadIdx.x;
  int lane = tid & 63, wid = tid >> 6;
  if (tid == 0) s_carry = 0;
  __syncthreads();
  for (int base = 0; base < N_NODES; base += 1024) {
    int i = base + tid;
    int v = (i < N_NODES) ? deg[i] : 0;
    int inc = v;
    #pragma unroll
    for (int off = 1; off < 64; off <<= 1) {
      int t = __shfl_up(inc, off, 64);
      if (lane >= off) inc += t;
    }
    if (lane == 63) wsum[wid] = inc;
    __syncthreads();
    if (wid == 0) {
      int wv = (lane < 16) ? wsum[lane] : 0;
      #pragma unroll
      for (int off = 1; off < 16; off <<= 1) {
        int t = __shfl_up(wv, off, 64);
        if (lane >= off) wv += t;
      }
      if (lane < 16) wsum[lane] = wv;   // inclusive wave-total scan
    }
    __syncthreads();
    int woff = (wid > 0) ? wsum[wid - 1] : 0;
    int incl = s_carry + woff + inc;
    int excl = incl - v;
    if (i < N_NODES) { row_start[i] = excl; cursor[i] = excl; }
    __syncthreads();                    // everyone done reading s_carry / wsum
    if (tid == 1023) s_carry += wsum[15];
    __syncthreads();
  }
  if (tid == 0) row_start[N_NODES] = s_carry;  // == ET
}

__global__ void k_fill(const int* __restrict__ esrc, const int* __restrict__ edst,
                       int* __restrict__ cursor, int* __restrict__ csr_src) {
  int i = blockIdx.x * blockDim.x + threadIdx.x;
  if (i < ET) {
    int s, d;
    if (i < N_EDGES) { s = esrc[i]; d = edst[i]; }
    else             { s = d = i - N_EDGES; }       // self loop
    int pos = atomicAdd(&cursor[d], 1);
    csr_src[pos] = s;
  }
}

// ---------------- layer-0 GEMM (din=7): h = x @ W ; as = h@a_src ; ad = h@a_dst ----------------

template<int DIN, int NPB>
__global__ __launch_bounds__(128) void k_gemm_small(const float* __restrict__ x,
                                                    const float* __restrict__ W,
                                                    const float* __restrict__ a_s,
                                                    const float* __restrict__ a_d,
                                                    float* __restrict__ h,
                                                    float* __restrict__ as_,
                                                    float* __restrict__ ad_) {
  __shared__ float Ws[DIN * HID];
  __shared__ float xs[DIN];
  __shared__ float red[4];
  int tid = threadIdx.x;
  for (int i = tid; i < DIN * HID; i += 128) Ws[i] = W[i];
  float asf = a_s[tid], adf = a_d[tid];
  int node0 = blockIdx.x * NPB;
  for (int nn = 0; nn < NPB; ++nn) {
    int node = node0 + nn;
    if (node >= N_NODES) break;          // uniform across block
    __syncthreads();                     // covers Ws staging (first iter) + xs/red reuse
    if (tid < DIN) xs[tid] = x[(size_t)node * DIN + tid];
    __syncthreads();
    float acc = 0.f;
    #pragma unroll
    for (int k = 0; k < DIN; ++k) acc = fmaf(xs[k], Ws[k * HID + tid], acc);
    h[(size_t)node * HID + tid] = acc;
    float vs = acc * asf, vd = acc * adf;
    #pragma unroll
    for (int off = 32; off >= 1; off >>= 1) {
      vs += __shfl_xor(vs, off, 64);
      vd += __shfl_xor(vd, off, 64);
    }
    int lane = tid & 63, wid = tid >> 6;
    if (lane == 0) { red[wid * 2] = vs; red[wid * 2 + 1] = vd; }
    __syncthreads();
    if (tid == 0)      as_[node] = red[0] + red[2];
    else if (tid == 1) ad_[node] = red[1] + red[3];
  }
}

// ---------------- hidden GEMM (din=128): W column in VGPRs, x tile staged in LDS ----------------
// Per thread: wreg[128] = W[:,tid] (loaded once per block, coalesced across the wave).
// Per block: stage NPB=32 x-rows (16KB) in LDS once, then the 32-node loop has no barriers;
// x is consumed as broadcast float4 ds_reads (conflict-free). Inner loop is pure
// v_fma with register W operand -> VALU-bound, not LDS-bound.

#define GNPB 32

__global__ __launch_bounds__(128, 2) void k_gemm128(const float* __restrict__ x,
                                                    const float* __restrict__ W,
                                                    const float* __restrict__ a_s,
                                                    const float* __restrict__ a_d,
                                                    float* __restrict__ h,
                                                    float* __restrict__ as_,
                                                    float* __restrict__ ad_) {
  __shared__ float4 xs4[GNPB * 32];     // 32 rows x 128 floats = 16KB
  __shared__ float red[GNPB][4];        // per-node {vs,vd} per wave
  int tid = threadIdx.x;
  int lane = tid & 63, wid = tid >> 6;

  float wreg[HID];
  #pragma unroll
  for (int k = 0; k < HID; ++k) wreg[k] = W[(size_t)k * HID + tid];
  float asf = a_s[tid], adf = a_d[tid];

  int node0 = blockIdx.x * GNPB;
  int rows = N_NODES - node0; if (rows > GNPB) rows = GNPB;

  const float4* xg = (const float4*)(x + (size_t)node0 * HID);
  for (int j = tid; j < rows * 32; j += 128) xs4[j] = xg[j];   // coalesced float4 staging
  __syncthreads();

  for (int nn = 0; nn < rows; ++nn) {
    float acc = 0.f;
    #pragma unroll
    for (int k4 = 0; k4 < 32; ++k4) {
      float4 xv = xs4[nn * 32 + k4];    // broadcast b128 read
      acc = fmaf(xv.x, wreg[4 * k4 + 0], acc);
      acc = fmaf(xv.y, wreg[4 * k4 + 1], acc);
      acc = fmaf(xv.z, wreg[4 * k4 + 2], acc);
      acc = fmaf(xv.w, wreg[4 * k4 + 3], acc);
    }
    h[(size_t)(node0 + nn) * HID + tid] = acc;
    float vs = acc * asf, vd = acc * adf;
    #pragma unroll
    for (int off = 32; off >= 1; off >>= 1) {
      vs += __shfl_xor(vs, off, 64);
      vd += __shfl_xor(vd, off, 64);
    }
    if (lane == 0) { red[nn][wid * 2] = vs; red[nn][wid * 2 + 1] = vd; }
  }
  __syncthreads();
  if (tid < rows) {
    as_[node0 + tid] = red[tid][0] + red[tid][2];
  } else if (tid >= 64 && tid - 64 < rows) {
    int nn = tid - 64;
    ad_[node0 + nn] = red[nn][1] + red[nn][3];
  }
}

// ---------------- atomic-free aggregation: wave per node, lanes = features (float2) ----------------

__global__ __launch_bounds__(256) void k_agg(const float* __restrict__ h,
                                             const float* __restrict__ as_,
                                             const float* __restrict__ ad_,
                                             const int* __restrict__ row_start,
                                             const int* __restrict__ csr_src,
                                             const float* __restrict__ b,
                                             float* __restrict__ out) {
  int wid = threadIdx.x >> 6, lane = threadIdx.x & 63;
  int node = blockIdx.x * 4 + wid;
  if (node >= N_NODES) return;
  int beg = row_start[node], end = row_start[node + 1];
  float adn = ad_[node];
  // pass 1: segment max (lane-parallel over edges)
  float m = -INFINITY;
  for (int i = beg + lane; i < end; i += 64) {
    float e = as_[csr_src[i]] + adn;
    e = e > 0.f ? e : NEG_SLOPE * e;
    m = fmaxf(m, e);
  }
  #pragma unroll
  for (int off = 32; off >= 1; off >>= 1) m = fmaxf(m, __shfl_xor(m, off, 64));
  // pass 2: edge-sequential, lanes = 64 float2 feature pairs; unnormalized accumulation
  float s = 0.f, a0 = 0.f, a1 = 0.f;
  const float2* h2 = (const float2*)h;
  for (int i = beg; i < end; ++i) {
    int sc = csr_src[i];                         // broadcast scalar load
    float e = as_[sc] + adn;
    e = e > 0.f ? e : NEG_SLOPE * e;
    float w = __expf(e - m);                     // same value in all lanes
    s += w;
    float2 hv = h2[(size_t)sc * 64 + lane];      // one dwordx2: full 512B row per wave
    a0 = fmaf(w, hv.x, a0);
    a1 = fmaf(w, hv.y, a1);
  }
  float inv = 1.f / (s + 1e-16f);
  float2 bv = ((const float2*)b)[lane];
  float v0 = a0 * inv + bv.x;
  float v1 = a1 * inv + bv.y;
  v0 = v0 > 0.f ? v0 : expm1f(v0);               // ELU
  v1 = v1 > 0.f ? v1 : expm1f(v1);
  float2 ov; ov.x = v0; ov.y = v1;
  ((float2*)out)[(size_t)node * 64 + lane] = ov;
}

// ---------------- mean-pool (sorted batch, binary search) + fc1/relu + fc2 + log_softmax ----------------

__global__ __launch_bounds__(128) void k_pool_mlp(const float* __restrict__ x,
                                                  const int* __restrict__ batch,
                                                  const float* __restrict__ fc1_w,
                                                  const float* __restrict__ fc1_b,
                                                  const float* __restrict__ fc2_w,
                                                  const float* __restrict__ fc2_b,
                                                  float* __restrict__ out) {
  __shared__ float g[HID];
  __shared__ float h1[HID];
  __shared__ float lgs[2];
  int gid = blockIdx.x, tid = threadIdx.x;
  // batch sorted ascending: [lo,hi) = nodes of graph gid
  int a = 0, bnd = N_NODES;
  while (a < bnd) { int mid = (a + bnd) >> 1; if (batch[mid] < gid) a = mid + 1; else bnd = mid; }
  int lo = a;
  bnd = N_NODES;
  while (a < bnd) { int mid = (a + bnd) >> 1; if (batch[mid] < gid + 1) a = mid + 1; else bnd = mid; }
  int hi = a;
  float acc = 0.f;
  for (int n = lo; n < hi; ++n) acc += x[(size_t)n * HID + tid];
  float cnt = (float)(hi - lo);
  g[tid] = acc / fmaxf(cnt, 1.f);
  __syncthreads();
  float a1 = fc1_b[tid];
  #pragma unroll 8
  for (int k = 0; k < HID; ++k) a1 = fmaf(g[k], fc1_w[k * FC + tid], a1);
  a1 = fmaxf(a1, 0.f);
  h1[tid] = a1;
  __syncthreads();
  int lane = tid & 63, w = tid >> 6;   // wave w computes logit w (2 classes)
  float p = h1[lane] * fc2_w[lane * 2 + w] + h1[64 + lane] * fc2_w[(64 + lane) * 2 + w];
  #pragma unroll
  for (int off = 32; off >= 1; off >>= 1) p += __shfl_xor(p, off, 64);
  if (lane == 0) lgs[w] = p + fc2_b[w];
  __syncthreads();
  if (tid == 0) {
    float l0 = lgs[0], l1 = lgs[1];
    float mx = fmaxf(l0, l1);
    float lse = mx + logf(expf(l0 - mx) + expf(l1 - mx));
    out[gid * 2 + 0] = l0 - lse;
    out[gid * 2 + 1] = l1 - lse;
  }
}

// ---------------- launch ----------------

extern "C" void kernel_launch(void* const* d_in, const int* in_sizes, int n_in,
                              void* d_out, int out_size, void* d_ws, size_t ws_size,
                              hipStream_t stream) {
  const float* x_in  = (const float*)d_in[0];
  const int*   eidx  = (const int*)d_in[1];   // [2, N_EDGES] row-major: [0..E)=src, [E..2E)=dst
  const int*   batch = (const int*)d_in[2];
  const float* W0 = (const float*)d_in[3];
  const float* aS0 = (const float*)d_in[4];
  const float* aD0 = (const float*)d_in[5];
  const float* b0 = (const float*)d_in[6];
  const float* W1 = (const float*)d_in[7];
  const float* aS1 = (const float*)d_in[8];
  const float* aD1 = (const float*)d_in[9];
  const float* b1 = (const float*)d_in[10];
  const float* W2 = (const float*)d_in[11];
  const float* aS2 = (const float*)d_in[12];
  const float* aD2 = (const float*)d_in[13];
  const float* b2 = (const float*)d_in[14];
  const float* fc1_w = (const float*)d_in[15];
  const float* fc1_b = (const float*)d_in[16];
  const float* fc2_w = (const float*)d_in[17];
  const float* fc2_b = (const float*)d_in[18];
  float* out = (float*)d_out;

  char* ws = (char*)d_ws;
  float* h   = (float*)ws;  ws += (size_t)N_NODES * HID * sizeof(float);
  float* xb  = (float*)ws;  ws += (size_t)N_NODES * HID * sizeof(float);
  float* as_ = (float*)ws;  ws += (size_t)N_NODES * sizeof(float);
  float* ad_ = (float*)ws;  ws += (size_t)N_NODES * sizeof(float);
  int* row_start = (int*)ws; ws += (size_t)(N_NODES + 1) * sizeof(int);
  int* cursor    = (int*)ws; ws += (size_t)N_NODES * sizeof(int);
  int* deg       = (int*)ws; ws += (size_t)N_NODES * sizeof(int);
  int* csr_src   = (int*)ws; ws += (size_t)ET * sizeof(int);

  const int* esrc = eidx;
  const int* edst = eidx + N_EDGES;

  // CSR build (edges identical for all 3 layers)
  k_init_deg<<<(N_NODES + 255) / 256, 256, 0, stream>>>(deg);
  k_hist<<<(N_EDGES + 255) / 256, 256, 0, stream>>>(edst, deg);
  k_scan<<<1, 1024, 0, stream>>>(deg, row_start, cursor);
  k_fill<<<(ET + 255) / 256, 256, 0, stream>>>(esrc, edst, cursor, csr_src);

  int gemm_grid = (N_NODES + GNPB - 1) / GNPB;
  int agg_grid = (N_NODES + 3) / 4;

  // layer 0 (din=7)
  k_gemm_small<IN_CH, 32><<<gemm_grid, 128, 0, stream>>>(x_in, W0, aS0, aD0, h, as_, ad_);
  k_agg<<<agg_grid, 256, 0, stream>>>(h, as_, ad_, row_start, csr_src, b0, xb);
  // layer 1
  k_gemm128<<<gemm_grid, 128, 0, stream>>>(xb, W1, aS1, aD1, h, as_, ad_);
  k_agg<<<agg_grid, 256, 0, stream>>>(h, as_, ad_, row_start, csr_src, b1, xb);
  // layer 2
  k_gemm128<<<gemm_grid, 128, 0, stream>>>(xb, W2, aS2, aD2, h, as_, ad_);
  k_agg<<<agg_grid, 256, 0, stream>>>(h, as_, ad_, row_start, csr_src, b2, xb);

  // head
  k_pool_mlp<<<N_GRAPHS, 128, 0, stream>>>(xb, batch, fc1_w, fc1_b, fc2_w, fc2_b, out);
}

// Round 4
// 622.777 us; speedup vs baseline: 1.1865x; 1.1865x over previous
//
#include <hip/hip_runtime.h>
#include <math.h>

#define N_NODES 50000
#define N_EDGES 800000
#define N_GRAPHS 512
#define IN_CH 7
#define HID 128
#define FC 128
#define ET (N_EDGES + N_NODES)   // real edges + self loops
#define NEG_SLOPE 0.2f

// ---------------- CSR build (once per call; edges identical across layers) ----------------

__global__ void k_init_deg(int* __restrict__ deg) {
  int i = blockIdx.x * blockDim.x + threadIdx.x;
  if (i < N_NODES) deg[i] = 1;  // self-loop contributes 1 incoming edge per node
}

__global__ void k_hist(const int* __restrict__ dst, int* __restrict__ deg) {
  int i = blockIdx.x * blockDim.x + threadIdx.x;
  if (i < N_EDGES) atomicAdd(&deg[dst[i]], 1);
}

// single-block hierarchical exclusive scan over N_NODES degrees
__global__ __launch_bounds__(1024) void k_scan(const int* __restrict__ deg,
                                               int* __restrict__ row_start,
                                               int* __restrict__ cursor) {
  __shared__ int wsum[16];
  __shared__ int s_carry;
  int tid = threadIdx.x;
  int lane = tid & 63, wid = tid >> 6;
  if (tid == 0) s_carry = 0;
  __syncthreads();
  for (int base = 0; base < N_NODES; base += 1024) {
    int i = base + tid;
    int v = (i < N_NODES) ? deg[i] : 0;
    int inc = v;
    #pragma unroll
    for (int off = 1; off < 64; off <<= 1) {
      int t = __shfl_up(inc, off, 64);
      if (lane >= off) inc += t;
    }
    if (lane == 63) wsum[wid] = inc;
    __syncthreads();
    if (wid == 0) {
      int wv = (lane < 16) ? wsum[lane] : 0;
      #pragma unroll
      for (int off = 1; off < 16; off <<= 1) {
        int t = __shfl_up(wv, off, 64);
        if (lane >= off) wv += t;
      }
      if (lane < 16) wsum[lane] = wv;   // inclusive wave-total scan
    }
    __syncthreads();
    int woff = (wid > 0) ? wsum[wid - 1] : 0;
    int incl = s_carry + woff + inc;
    int excl = incl - v;
    if (i < N_NODES) { row_start[i] = excl; cursor[i] = excl; }
    __syncthreads();                    // everyone done reading s_carry / wsum
    if (tid == 1023) s_carry += wsum[15];
    __syncthreads();
  }
  if (tid == 0) row_start[N_NODES] = s_carry;  // == ET
}

__global__ void k_fill(const int* __restrict__ esrc, const int* __restrict__ edst,
                       int* __restrict__ cursor, int* __restrict__ csr_src) {
  int i = blockIdx.x * blockDim.x + threadIdx.x;
  if (i < ET) {
    int s, d;
    if (i < N_EDGES) { s = esrc[i]; d = edst[i]; }
    else             { s = d = i - N_EDGES; }       // self loop
    int pos = atomicAdd(&cursor[d], 1);
    csr_src[pos] = s;
  }
}

// ---------------- layer-0 GEMM (din=7): h = x @ W ; as = h@a_src ; ad = h@a_dst ----------------

template<int DIN, int NPB>
__global__ __launch_bounds__(128) void k_gemm_small(const float* __restrict__ x,
                                                    const float* __restrict__ W,
                                                    const float* __restrict__ a_s,
                                                    const float* __restrict__ a_d,
                                                    float* __restrict__ h,
                                                    float* __restrict__ as_,
                                                    float* __restrict__ ad_) {
  __shared__ float Ws[DIN * HID];
  __shared__ float xs[DIN];
  __shared__ float red[4];
  int tid = threadIdx.x;
  for (int i = tid; i < DIN * HID; i += 128) Ws[i] = W[i];
  float asf = a_s[tid], adf = a_d[tid];
  int node0 = blockIdx.x * NPB;
  for (int nn = 0; nn < NPB; ++nn) {
    int node = node0 + nn;
    if (node >= N_NODES) break;          // uniform across block
    __syncthreads();                     // covers Ws staging (first iter) + xs/red reuse
    if (tid < DIN) xs[tid] = x[(size_t)node * DIN + tid];
    __syncthreads();
    float acc = 0.f;
    #pragma unroll
    for (int k = 0; k < DIN; ++k) acc = fmaf(xs[k], Ws[k * HID + tid], acc);
    h[(size_t)node * HID + tid] = acc;
    float vs = acc * asf, vd = acc * adf;
    #pragma unroll
    for (int off = 32; off >= 1; off >>= 1) {
      vs += __shfl_xor(vs, off, 64);
      vd += __shfl_xor(vd, off, 64);
    }
    int lane = tid & 63, wid = tid >> 6;
    if (lane == 0) { red[wid * 2] = vs; red[wid * 2 + 1] = vd; }
    __syncthreads();
    if (tid == 0)      as_[node] = red[0] + red[2];
    else if (tid == 1) ad_[node] = red[1] + red[3];
  }
}

// ---------------- hidden GEMM (din=128): W column in VGPRs, x tile staged in LDS ----------------

#define GNPB 32

__global__ __launch_bounds__(128, 2) void k_gemm128(const float* __restrict__ x,
                                                    const float* __restrict__ W,
                                                    const float* __restrict__ a_s,
                                                    const float* __restrict__ a_d,
                                                    float* __restrict__ h,
                                                    float* __restrict__ as_,
                                                    float* __restrict__ ad_) {
  __shared__ float4 xs4[GNPB * 32];     // 32 rows x 128 floats = 16KB
  __shared__ float red[GNPB][4];        // per-node {vs,vd} per wave
  int tid = threadIdx.x;
  int lane = tid & 63, wid = tid >> 6;

  float wreg[HID];
  #pragma unroll
  for (int k = 0; k < HID; ++k) wreg[k] = W[(size_t)k * HID + tid];
  float asf = a_s[tid], adf = a_d[tid];

  int node0 = blockIdx.x * GNPB;
  int rows = N_NODES - node0; if (rows > GNPB) rows = GNPB;

  const float4* xg = (const float4*)(x + (size_t)node0 * HID);
  for (int j = tid; j < rows * 32; j += 128) xs4[j] = xg[j];   // coalesced float4 staging
  __syncthreads();

  for (int nn = 0; nn < rows; ++nn) {
    float acc = 0.f;
    #pragma unroll
    for (int k4 = 0; k4 < 32; ++k4) {
      float4 xv = xs4[nn * 32 + k4];    // broadcast b128 read
      acc = fmaf(xv.x, wreg[4 * k4 + 0], acc);
      acc = fmaf(xv.y, wreg[4 * k4 + 1], acc);
      acc = fmaf(xv.z, wreg[4 * k4 + 2], acc);
      acc = fmaf(xv.w, wreg[4 * k4 + 3], acc);
    }
    h[(size_t)(node0 + nn) * HID + tid] = acc;
    float vs = acc * asf, vd = acc * adf;
    #pragma unroll
    for (int off = 32; off >= 1; off >>= 1) {
      vs += __shfl_xor(vs, off, 64);
      vd += __shfl_xor(vd, off, 64);
    }
    if (lane == 0) { red[nn][wid * 2] = vs; red[nn][wid * 2 + 1] = vd; }
  }
  __syncthreads();
  if (tid < rows) {
    as_[node0 + tid] = red[tid][0] + red[tid][2];
  } else if (tid >= 64 && tid - 64 < rows) {
    int nn = tid - 64;
    ad_[node0 + nn] = red[nn][1] + red[nn][3];
  }
}

// ---------------- atomic-free aggregation: wave per node, lanes = features ----------------
// Fast path (deg<=64, always true for this input): lane-parallel softmax entirely in
// registers (one load round-trip), then pass 2 = pure independent h-row gathers with
// wave-uniform (readlane) weights -> no dependent-load chain, 4 gathers in flight.

__global__ __launch_bounds__(256) void k_agg(const float* __restrict__ h,
                                             const float* __restrict__ as_,
                                             const float* __restrict__ ad_,
                                             const int* __restrict__ row_start,
                                             const int* __restrict__ csr_src,
                                             const float* __restrict__ b,
                                             float* __restrict__ out) {
  int wid = threadIdx.x >> 6, lane = threadIdx.x & 63;
  int node = blockIdx.x * 4 + wid;
  if (node >= N_NODES) return;
  int beg = row_start[node], end = row_start[node + 1];
  int n = end - beg;                     // >= 1 (self-loop)
  float adn = ad_[node];
  const float2* h2 = (const float2*)h;
  float a0 = 0.f, a1 = 0.f, c0 = 0.f, c1 = 0.f;
  float inv;

  if (n <= 64) {
    // --- fast path: lane j owns edge beg+j ---
    int sc_l = csr_src[beg + (lane < n ? lane : n - 1)];
    float e = as_[sc_l] + adn;
    e = e > 0.f ? e : NEG_SLOPE * e;
    float m = (lane < n) ? e : -INFINITY;
    #pragma unroll
    for (int off = 32; off >= 1; off >>= 1) m = fmaxf(m, __shfl_xor(m, off, 64));
    float we = (lane < n) ? __expf(e - m) : 0.f;
    float s = we;
    #pragma unroll
    for (int off = 32; off >= 1; off >>= 1) s += __shfl_xor(s, off, 64);
    inv = 1.f / (s + 1e-16f);
    int wbits = __float_as_int(we);

    int j = 0;
    for (; j + 4 <= n; j += 4) {         // 4 independent gathers in flight
      int s0 = __builtin_amdgcn_readlane(sc_l, j);
      int s1 = __builtin_amdgcn_readlane(sc_l, j + 1);
      int s2 = __builtin_amdgcn_readlane(sc_l, j + 2);
      int s3 = __builtin_amdgcn_readlane(sc_l, j + 3);
      float w0 = __int_as_float(__builtin_amdgcn_readlane(wbits, j));
      float w1 = __int_as_float(__builtin_amdgcn_readlane(wbits, j + 1));
      float w2 = __int_as_float(__builtin_amdgcn_readlane(wbits, j + 2));
      float w3 = __int_as_float(__builtin_amdgcn_readlane(wbits, j + 3));
      float2 h0 = h2[(size_t)s0 * 64 + lane];
      float2 h1 = h2[(size_t)s1 * 64 + lane];
      float2 hh2 = h2[(size_t)s2 * 64 + lane];
      float2 h3 = h2[(size_t)s3 * 64 + lane];
      a0 = fmaf(w0, h0.x, a0);  a1 = fmaf(w0, h0.y, a1);
      c0 = fmaf(w1, h1.x, c0);  c1 = fmaf(w1, h1.y, c1);
      a0 = fmaf(w2, hh2.x, a0); a1 = fmaf(w2, hh2.y, a1);
      c0 = fmaf(w3, h3.x, c0);  c1 = fmaf(w3, h3.y, c1);
    }
    for (; j < n; ++j) {
      int sj = __builtin_amdgcn_readlane(sc_l, j);
      float wj = __int_as_float(__builtin_amdgcn_readlane(wbits, j));
      float2 hv = h2[(size_t)sj * 64 + lane];
      a0 = fmaf(wj, hv.x, a0);  a1 = fmaf(wj, hv.y, a1);
    }
  } else {
    // --- generic path (deg > 64): original two-pass ---
    float m = -INFINITY;
    for (int i = beg + lane; i < end; i += 64) {
      float e = as_[csr_src[i]] + adn;
      e = e > 0.f ? e : NEG_SLOPE * e;
      m = fmaxf(m, e);
    }
    #pragma unroll
    for (int off = 32; off >= 1; off >>= 1) m = fmaxf(m, __shfl_xor(m, off, 64));
    float s = 0.f;
    for (int i = beg; i < end; ++i) {
      int sc = csr_src[i];
      float e = as_[sc] + adn;
      e = e > 0.f ? e : NEG_SLOPE * e;
      float w = __expf(e - m);
      s += w;
      float2 hv = h2[(size_t)sc * 64 + lane];
      a0 = fmaf(w, hv.x, a0);
      a1 = fmaf(w, hv.y, a1);
    }
    inv = 1.f / (s + 1e-16f);
  }

  float2 bv = ((const float2*)b)[lane];
  float v0 = (a0 + c0) * inv + bv.x;
  float v1 = (a1 + c1) * inv + bv.y;
  v0 = v0 > 0.f ? v0 : expm1f(v0);       // ELU
  v1 = v1 > 0.f ? v1 : expm1f(v1);
  float2 ov; ov.x = v0; ov.y = v1;
  ((float2*)out)[(size_t)node * 64 + lane] = ov;
}

// ---------------- mean-pool (sorted batch, binary search) + fc1/relu + fc2 + log_softmax ----------------

__global__ __launch_bounds__(128) void k_pool_mlp(const float* __restrict__ x,
                                                  const int* __restrict__ batch,
                                                  const float* __restrict__ fc1_w,
                                                  const float* __restrict__ fc1_b,
                                                  const float* __restrict__ fc2_w,
                                                  const float* __restrict__ fc2_b,
                                                  float* __restrict__ out) {
  __shared__ float g[HID];
  __shared__ float h1[HID];
  __shared__ float lgs[2];
  int gid = blockIdx.x, tid = threadIdx.x;
  int a = 0, bnd = N_NODES;
  while (a < bnd) { int mid = (a + bnd) >> 1; if (batch[mid] < gid) a = mid + 1; else bnd = mid; }
  int lo = a;
  bnd = N_NODES;
  while (a < bnd) { int mid = (a + bnd) >> 1; if (batch[mid] < gid + 1) a = mid + 1; else bnd = mid; }
  int hi = a;
  float acc = 0.f;
  for (int n = lo; n < hi; ++n) acc += x[(size_t)n * HID + tid];
  float cnt = (float)(hi - lo);
  g[tid] = acc / fmaxf(cnt, 1.f);
  __syncthreads();
  float a1 = fc1_b[tid];
  #pragma unroll 8
  for (int k = 0; k < HID; ++k) a1 = fmaf(g[k], fc1_w[k * FC + tid], a1);
  a1 = fmaxf(a1, 0.f);
  h1[tid] = a1;
  __syncthreads();
  int lane = tid & 63, w = tid >> 6;   // wave w computes logit w (2 classes)
  float p = h1[lane] * fc2_w[lane * 2 + w] + h1[64 + lane] * fc2_w[(64 + lane) * 2 + w];
  #pragma unroll
  for (int off = 32; off >= 1; off >>= 1) p += __shfl_xor(p, off, 64);
  if (lane == 0) lgs[w] = p + fc2_b[w];
  __syncthreads();
  if (tid == 0) {
    float l0 = lgs[0], l1 = lgs[1];
    float mx = fmaxf(l0, l1);
    float lse = mx + logf(expf(l0 - mx) + expf(l1 - mx));
    out[gid * 2 + 0] = l0 - lse;
    out[gid * 2 + 1] = l1 - lse;
  }
}

// ---------------- launch ----------------

extern "C" void kernel_launch(void* const* d_in, const int* in_sizes, int n_in,
                              void* d_out, int out_size, void* d_ws, size_t ws_size,
                              hipStream_t stream) {
  const float* x_in  = (const float*)d_in[0];
  const int*   eidx  = (const int*)d_in[1];   // [2, N_EDGES]: [0..E)=src, [E..2E)=dst
  const int*   batch = (const int*)d_in[2];
  const float* W0 = (const float*)d_in[3];
  const float* aS0 = (const float*)d_in[4];
  const float* aD0 = (const float*)d_in[5];
  const float* b0 = (const float*)d_in[6];
  const float* W1 = (const float*)d_in[7];
  const float* aS1 = (const float*)d_in[8];
  const float* aD1 = (const float*)d_in[9];
  const float* b1 = (const float*)d_in[10];
  const float* W2 = (const float*)d_in[11];
  const float* aS2 = (const float*)d_in[12];
  const float* aD2 = (const float*)d_in[13];
  const float* b2 = (const float*)d_in[14];
  const float* fc1_w = (const float*)d_in[15];
  const float* fc1_b = (const float*)d_in[16];
  const float* fc2_w = (const float*)d_in[17];
  const float* fc2_b = (const float*)d_in[18];
  float* out = (float*)d_out;

  char* ws = (char*)d_ws;
  float* h   = (float*)ws;  ws += (size_t)N_NODES * HID * sizeof(float);
  float* xb  = (float*)ws;  ws += (size_t)N_NODES * HID * sizeof(float);
  float* as_ = (float*)ws;  ws += (size_t)N_NODES * sizeof(float);
  float* ad_ = (float*)ws;  ws += (size_t)N_NODES * sizeof(float);
  int* row_start = (int*)ws; ws += (size_t)(N_NODES + 1) * sizeof(int);
  int* cursor    = (int*)ws; ws += (size_t)N_NODES * sizeof(int);
  int* deg       = (int*)ws; ws += (size_t)N_NODES * sizeof(int);
  int* csr_src   = (int*)ws; ws += (size_t)ET * sizeof(int);

  const int* esrc = eidx;
  const int* edst = eidx + N_EDGES;

  // CSR build (edges identical for all 3 layers)
  k_init_deg<<<(N_NODES + 255) / 256, 256, 0, stream>>>(deg);
  k_hist<<<(N_EDGES + 255) / 256, 256, 0, stream>>>(edst, deg);
  k_scan<<<1, 1024, 0, stream>>>(deg, row_start, cursor);
  k_fill<<<(ET + 255) / 256, 256, 0, stream>>>(esrc, edst, cursor, csr_src);

  int gemm_grid = (N_NODES + GNPB - 1) / GNPB;
  int agg_grid = (N_NODES + 3) / 4;

  // layer 0 (din=7)
  k_gemm_small<IN_CH, 32><<<gemm_grid, 128, 0, stream>>>(x_in, W0, aS0, aD0, h, as_, ad_);
  k_agg<<<agg_grid, 256, 0, stream>>>(h, as_, ad_, row_start, csr_src, b0, xb);
  // layer 1
  k_gemm128<<<gemm_grid, 128, 0, stream>>>(xb, W1, aS1, aD1, h, as_, ad_);
  k_agg<<<agg_grid, 256, 0, stream>>>(h, as_, ad_, row_start, csr_src, b1, xb);
  // layer 2
  k_gemm128<<<gemm_grid, 128, 0, stream>>>(xb, W2, aS2, aD2, h, as_, ad_);
  k_agg<<<agg_grid, 256, 0, stream>>>(h, as_, ad_, row_start, csr_src, b2, xb);

  // head
  k_pool_mlp<<<N_GRAPHS, 128, 0, stream>>>(xb, batch, fc1_w, fc1_b, fc2_w, fc2_b, out);
}

// Round 5
// 570.067 us; speedup vs baseline: 1.2962x; 1.0925x over previous
//
#include <hip/hip_runtime.h>
#include <math.h>

#define N_NODES 50000
#define N_EDGES 800000
#define N_GRAPHS 512
#define IN_CH 7
#define HID 128
#define FC 128
#define ET (N_EDGES + N_NODES)   // real edges + self loops
#define NEG_SLOPE 0.2f

// ---------------- CSR build (once per call; edges identical across layers) ----------------

__global__ void k_init_deg(int* __restrict__ deg) {
  int i = blockIdx.x * blockDim.x + threadIdx.x;
  if (i < N_NODES) deg[i] = 1;  // self-loop contributes 1 incoming edge per node
}

__global__ void k_hist(const int* __restrict__ dst, int* __restrict__ deg) {
  int i = blockIdx.x * blockDim.x + threadIdx.x;
  if (i < N_EDGES) atomicAdd(&deg[dst[i]], 1);
}

// single-block hierarchical exclusive scan over N_NODES degrees
__global__ __launch_bounds__(1024) void k_scan(const int* __restrict__ deg,
                                               int* __restrict__ row_start,
                                               int* __restrict__ cursor) {
  __shared__ int wsum[16];
  __shared__ int s_carry;
  int tid = threadIdx.x;
  int lane = tid & 63, wid = tid >> 6;
  if (tid == 0) s_carry = 0;
  __syncthreads();
  for (int base = 0; base < N_NODES; base += 1024) {
    int i = base + tid;
    int v = (i < N_NODES) ? deg[i] : 0;
    int inc = v;
    #pragma unroll
    for (int off = 1; off < 64; off <<= 1) {
      int t = __shfl_up(inc, off, 64);
      if (lane >= off) inc += t;
    }
    if (lane == 63) wsum[wid] = inc;
    __syncthreads();
    if (wid == 0) {
      int wv = (lane < 16) ? wsum[lane] : 0;
      #pragma unroll
      for (int off = 1; off < 16; off <<= 1) {
        int t = __shfl_up(wv, off, 64);
        if (lane >= off) wv += t;
      }
      if (lane < 16) wsum[lane] = wv;   // inclusive wave-total scan
    }
    __syncthreads();
    int woff = (wid > 0) ? wsum[wid - 1] : 0;
    int incl = s_carry + woff + inc;
    int excl = incl - v;
    if (i < N_NODES) { row_start[i] = excl; cursor[i] = excl; }
    __syncthreads();                    // everyone done reading s_carry / wsum
    if (tid == 1023) s_carry += wsum[15];
    __syncthreads();
  }
  if (tid == 0) row_start[N_NODES] = s_carry;  // == ET
}

__global__ void k_fill(const int* __restrict__ esrc, const int* __restrict__ edst,
                       int* __restrict__ cursor, int* __restrict__ csr_src) {
  int i = blockIdx.x * blockDim.x + threadIdx.x;
  if (i < ET) {
    int s, d;
    if (i < N_EDGES) { s = esrc[i]; d = edst[i]; }
    else             { s = d = i - N_EDGES; }       // self loop
    int pos = atomicAdd(&cursor[d], 1);
    csr_src[pos] = s;
  }
}

__global__ void k_zero(float* __restrict__ p, int n) {
  int i = blockIdx.x * blockDim.x + threadIdx.x;
  if (i < n) p[i] = 0.f;
}

// ---------------- layer-0 GEMM (din=7): h = x @ W ; as = h@a_src ; ad = h@a_dst ----------------

template<int DIN, int NPB>
__global__ __launch_bounds__(128) void k_gemm_small(const float* __restrict__ x,
                                                    const float* __restrict__ W,
                                                    const float* __restrict__ a_s,
                                                    const float* __restrict__ a_d,
                                                    float* __restrict__ h,
                                                    float* __restrict__ as_,
                                                    float* __restrict__ ad_) {
  __shared__ float Ws[DIN * HID];
  __shared__ float xs[DIN];
  __shared__ float red[4];
  int tid = threadIdx.x;
  for (int i = tid; i < DIN * HID; i += 128) Ws[i] = W[i];
  float asf = a_s[tid], adf = a_d[tid];
  int node0 = blockIdx.x * NPB;
  for (int nn = 0; nn < NPB; ++nn) {
    int node = node0 + nn;
    if (node >= N_NODES) break;          // uniform across block
    __syncthreads();                     // covers Ws staging (first iter) + xs/red reuse
    if (tid < DIN) xs[tid] = x[(size_t)node * DIN + tid];
    __syncthreads();
    float acc = 0.f;
    #pragma unroll
    for (int k = 0; k < DIN; ++k) acc = fmaf(xs[k], Ws[k * HID + tid], acc);
    h[(size_t)node * HID + tid] = acc;
    float vs = acc * asf, vd = acc * adf;
    #pragma unroll
    for (int off = 32; off >= 1; off >>= 1) {
      vs += __shfl_xor(vs, off, 64);
      vd += __shfl_xor(vd, off, 64);
    }
    int lane = tid & 63, wid = tid >> 6;
    if (lane == 0) { red[wid * 2] = vs; red[wid * 2 + 1] = vd; }
    __syncthreads();
    if (tid == 0)      as_[node] = red[0] + red[2];
    else if (tid == 1) ad_[node] = red[1] + red[3];
  }
}

// ---------------- hidden GEMM (din=128): LDS-tiled, 4x4 register micro-tile ----------------
// Block tile: TM=64 nodes x TN=64 cols, 256 threads (16 col-groups x 16 node-groups).
// xT [k][node] transposed + Wl [k][col], both +4 pad (keeps float4 16B alignment, spreads
// banks). Per k: 2 ds_read_b128 feeding 16 independent FMA chains -> compute-bound, no
// reliance on compiler keeping a 128-reg array resident. Fused alpha partials via 16-lane
// shfl tree + one atomicAdd per node per col-block (2 commutative fp32 adds -> deterministic).

#define TM 64
#define TN 64

__global__ __launch_bounds__(256, 2) void k_gemm128(const float* __restrict__ x,
                                                    const float* __restrict__ W,
                                                    const float* __restrict__ a_s,
                                                    const float* __restrict__ a_d,
                                                    float* __restrict__ h,
                                                    float* __restrict__ as_,
                                                    float* __restrict__ ad_) {
  __shared__ float xT[HID][TM + 4];     // 128 x 68 x 4B = 34.8KB
  __shared__ float Wl[HID][TN + 4];     // 34.8KB
  int tid = threadIdx.x;
  int node0 = blockIdx.x * TM;
  int col0  = blockIdx.y * TN;

  // stage x tile transposed: 64 rows x 128 k (coalesced float4 reads)
  {
    const float4* xg = (const float4*)x;
    #pragma unroll
    for (int it = 0; it < (TM * 32) / 256; ++it) {
      int idx = tid + it * 256;
      int r = idx >> 5, k4 = idx & 31;
      int node = node0 + r;
      float4 v = make_float4(0.f, 0.f, 0.f, 0.f);
      if (node < N_NODES) v = xg[(size_t)node * 32 + k4];
      xT[4 * k4 + 0][r] = v.x;
      xT[4 * k4 + 1][r] = v.y;
      xT[4 * k4 + 2][r] = v.z;
      xT[4 * k4 + 3][r] = v.w;
    }
  }
  // stage W slice: 128 k x 64 cols (row-major, cols contiguous -> b128 writes)
  {
    const float4* wg = (const float4*)W;
    #pragma unroll
    for (int it = 0; it < (HID * (TN / 4)) / 256; ++it) {
      int idx = tid + it * 256;
      int k = idx >> 4, c4 = idx & 15;
      float4 v = wg[(size_t)k * 32 + (col0 >> 2) + c4];
      *(float4*)&Wl[k][4 * c4] = v;
    }
  }
  __syncthreads();

  int cg = tid & 15;        // col group: cols col0 + 4*cg .. +3
  int nr = tid >> 4;        // node group: nodes node0 + 4*nr .. +3
  float acc00 = 0.f, acc01 = 0.f, acc02 = 0.f, acc03 = 0.f;
  float acc10 = 0.f, acc11 = 0.f, acc12 = 0.f, acc13 = 0.f;
  float acc20 = 0.f, acc21 = 0.f, acc22 = 0.f, acc23 = 0.f;
  float acc30 = 0.f, acc31 = 0.f, acc32 = 0.f, acc33 = 0.f;

  #pragma unroll 8
  for (int k = 0; k < HID; ++k) {
    float4 xv = *(const float4*)&xT[k][nr * 4];
    float4 wv = *(const float4*)&Wl[k][cg * 4];
    acc00 = fmaf(xv.x, wv.x, acc00); acc01 = fmaf(xv.x, wv.y, acc01);
    acc02 = fmaf(xv.x, wv.z, acc02); acc03 = fmaf(xv.x, wv.w, acc03);
    acc10 = fmaf(xv.y, wv.x, acc10); acc11 = fmaf(xv.y, wv.y, acc11);
    acc12 = fmaf(xv.y, wv.z, acc12); acc13 = fmaf(xv.y, wv.w, acc13);
    acc20 = fmaf(xv.z, wv.x, acc20); acc21 = fmaf(xv.z, wv.y, acc21);
    acc22 = fmaf(xv.z, wv.z, acc22); acc23 = fmaf(xv.z, wv.w, acc23);
    acc30 = fmaf(xv.w, wv.x, acc30); acc31 = fmaf(xv.w, wv.y, acc31);
    acc32 = fmaf(xv.w, wv.z, acc32); acc33 = fmaf(xv.w, wv.w, acc33);
  }

  // epilogue: store h + fused alpha partials
  float as0 = a_s[col0 + 4 * cg + 0], as1 = a_s[col0 + 4 * cg + 1];
  float as2 = a_s[col0 + 4 * cg + 2], as3 = a_s[col0 + 4 * cg + 3];
  float ad0 = a_d[col0 + 4 * cg + 0], ad1 = a_d[col0 + 4 * cg + 1];
  float ad2 = a_d[col0 + 4 * cg + 2], ad3 = a_d[col0 + 4 * cg + 3];

  #pragma unroll
  for (int i = 0; i < 4; ++i) {
    float r0 = (i == 0) ? acc00 : (i == 1) ? acc10 : (i == 2) ? acc20 : acc30;
    float r1 = (i == 0) ? acc01 : (i == 1) ? acc11 : (i == 2) ? acc21 : acc31;
    float r2 = (i == 0) ? acc02 : (i == 1) ? acc12 : (i == 2) ? acc22 : acc32;
    float r3 = (i == 0) ? acc03 : (i == 1) ? acc13 : (i == 2) ? acc23 : acc33;
    int node = node0 + nr * 4 + i;
    float ps = fmaf(r0, as0, fmaf(r1, as1, fmaf(r2, as2, r3 * as3)));
    float pd = fmaf(r0, ad0, fmaf(r1, ad1, fmaf(r2, ad2, r3 * ad3)));
    #pragma unroll
    for (int off = 1; off < 16; off <<= 1) {
      ps += __shfl_xor(ps, off, 16);
      pd += __shfl_xor(pd, off, 16);
    }
    if (node < N_NODES) {
      float4 hv; hv.x = r0; hv.y = r1; hv.z = r2; hv.w = r3;
      *(float4*)&h[(size_t)node * HID + col0 + 4 * cg] = hv;
      if (cg == 0) {
        atomicAdd(&as_[node], ps);
        atomicAdd(&ad_[node], pd);
      }
    }
  }
}

// ---------------- atomic-free aggregation: wave per node, lanes = features ----------------
// Fast path (deg<=64, always true for this input): lane-parallel softmax entirely in
// registers (one load round-trip), then pass 2 = pure independent h-row gathers with
// wave-uniform (readlane) weights -> no dependent-load chain, 4 gathers in flight.

__global__ __launch_bounds__(256) void k_agg(const float* __restrict__ h,
                                             const float* __restrict__ as_,
                                             const float* __restrict__ ad_,
                                             const int* __restrict__ row_start,
                                             const int* __restrict__ csr_src,
                                             const float* __restrict__ b,
                                             float* __restrict__ out) {
  int wid = threadIdx.x >> 6, lane = threadIdx.x & 63;
  int node = blockIdx.x * 4 + wid;
  if (node >= N_NODES) return;
  int beg = row_start[node], end = row_start[node + 1];
  int n = end - beg;                     // >= 1 (self-loop)
  float adn = ad_[node];
  const float2* h2 = (const float2*)h;
  float a0 = 0.f, a1 = 0.f, c0 = 0.f, c1 = 0.f;
  float inv;

  if (n <= 64) {
    // --- fast path: lane j owns edge beg+j ---
    int sc_l = csr_src[beg + (lane < n ? lane : n - 1)];
    float e = as_[sc_l] + adn;
    e = e > 0.f ? e : NEG_SLOPE * e;
    float m = (lane < n) ? e : -INFINITY;
    #pragma unroll
    for (int off = 32; off >= 1; off >>= 1) m = fmaxf(m, __shfl_xor(m, off, 64));
    float we = (lane < n) ? __expf(e - m) : 0.f;
    float s = we;
    #pragma unroll
    for (int off = 32; off >= 1; off >>= 1) s += __shfl_xor(s, off, 64);
    inv = 1.f / (s + 1e-16f);
    int wbits = __float_as_int(we);

    int j = 0;
    for (; j + 4 <= n; j += 4) {         // 4 independent gathers in flight
      int s0 = __builtin_amdgcn_readlane(sc_l, j);
      int s1 = __builtin_amdgcn_readlane(sc_l, j + 1);
      int s2 = __builtin_amdgcn_readlane(sc_l, j + 2);
      int s3 = __builtin_amdgcn_readlane(sc_l, j + 3);
      float w0 = __int_as_float(__builtin_amdgcn_readlane(wbits, j));
      float w1 = __int_as_float(__builtin_amdgcn_readlane(wbits, j + 1));
      float w2 = __int_as_float(__builtin_amdgcn_readlane(wbits, j + 2));
      float w3 = __int_as_float(__builtin_amdgcn_readlane(wbits, j + 3));
      float2 h0 = h2[(size_t)s0 * 64 + lane];
      float2 h1 = h2[(size_t)s1 * 64 + lane];
      float2 hh2 = h2[(size_t)s2 * 64 + lane];
      float2 h3 = h2[(size_t)s3 * 64 + lane];
      a0 = fmaf(w0, h0.x, a0);  a1 = fmaf(w0, h0.y, a1);
      c0 = fmaf(w1, h1.x, c0);  c1 = fmaf(w1, h1.y, c1);
      a0 = fmaf(w2, hh2.x, a0); a1 = fmaf(w2, hh2.y, a1);
      c0 = fmaf(w3, h3.x, c0);  c1 = fmaf(w3, h3.y, c1);
    }
    for (; j < n; ++j) {
      int sj = __builtin_amdgcn_readlane(sc_l, j);
      float wj = __int_as_float(__builtin_amdgcn_readlane(wbits, j));
      float2 hv = h2[(size_t)sj * 64 + lane];
      a0 = fmaf(wj, hv.x, a0);  a1 = fmaf(wj, hv.y, a1);
    }
  } else {
    // --- generic path (deg > 64): original two-pass ---
    float m = -INFINITY;
    for (int i = beg + lane; i < end; i += 64) {
      float e = as_[csr_src[i]] + adn;
      e = e > 0.f ? e : NEG_SLOPE * e;
      m = fmaxf(m, e);
    }
    #pragma unroll
    for (int off = 32; off >= 1; off >>= 1) m = fmaxf(m, __shfl_xor(m, off, 64));
    float s = 0.f;
    for (int i = beg; i < end; ++i) {
      int sc = csr_src[i];
      float e = as_[sc] + adn;
      e = e > 0.f ? e : NEG_SLOPE * e;
      float w = __expf(e - m);
      s += w;
      float2 hv = h2[(size_t)sc * 64 + lane];
      a0 = fmaf(w, hv.x, a0);
      a1 = fmaf(w, hv.y, a1);
    }
    inv = 1.f / (s + 1e-16f);
  }

  float2 bv = ((const float2*)b)[lane];
  float v0 = (a0 + c0) * inv + bv.x;
  float v1 = (a1 + c1) * inv + bv.y;
  v0 = v0 > 0.f ? v0 : expm1f(v0);       // ELU
  v1 = v1 > 0.f ? v1 : expm1f(v1);
  float2 ov; ov.x = v0; ov.y = v1;
  ((float2*)out)[(size_t)node * 64 + lane] = ov;
}

// ---------------- mean-pool (sorted batch, binary search) + fc1/relu + fc2 + log_softmax ----------------

__global__ __launch_bounds__(128) void k_pool_mlp(const float* __restrict__ x,
                                                  const int* __restrict__ batch,
                                                  const float* __restrict__ fc1_w,
                                                  const float* __restrict__ fc1_b,
                                                  const float* __restrict__ fc2_w,
                                                  const float* __restrict__ fc2_b,
                                                  float* __restrict__ out) {
  __shared__ float g[HID];
  __shared__ float h1[HID];
  __shared__ float lgs[2];
  int gid = blockIdx.x, tid = threadIdx.x;
  int a = 0, bnd = N_NODES;
  while (a < bnd) { int mid = (a + bnd) >> 1; if (batch[mid] < gid) a = mid + 1; else bnd = mid; }
  int lo = a;
  bnd = N_NODES;
  while (a < bnd) { int mid = (a + bnd) >> 1; if (batch[mid] < gid + 1) a = mid + 1; else bnd = mid; }
  int hi = a;
  float acc = 0.f;
  for (int n = lo; n < hi; ++n) acc += x[(size_t)n * HID + tid];
  float cnt = (float)(hi - lo);
  g[tid] = acc / fmaxf(cnt, 1.f);
  __syncthreads();
  float a1 = fc1_b[tid];
  #pragma unroll 8
  for (int k = 0; k < HID; ++k) a1 = fmaf(g[k], fc1_w[k * FC + tid], a1);
  a1 = fmaxf(a1, 0.f);
  h1[tid] = a1;
  __syncthreads();
  int lane = tid & 63, w = tid >> 6;   // wave w computes logit w (2 classes)
  float p = h1[lane] * fc2_w[lane * 2 + w] + h1[64 + lane] * fc2_w[(64 + lane) * 2 + w];
  #pragma unroll
  for (int off = 32; off >= 1; off >>= 1) p += __shfl_xor(p, off, 64);
  if (lane == 0) lgs[w] = p + fc2_b[w];
  __syncthreads();
  if (tid == 0) {
    float l0 = lgs[0], l1 = lgs[1];
    float mx = fmaxf(l0, l1);
    float lse = mx + logf(expf(l0 - mx) + expf(l1 - mx));
    out[gid * 2 + 0] = l0 - lse;
    out[gid * 2 + 1] = l1 - lse;
  }
}

// ---------------- launch ----------------

extern "C" void kernel_launch(void* const* d_in, const int* in_sizes, int n_in,
                              void* d_out, int out_size, void* d_ws, size_t ws_size,
                              hipStream_t stream) {
  const float* x_in  = (const float*)d_in[0];
  const int*   eidx  = (const int*)d_in[1];   // [2, N_EDGES]: [0..E)=src, [E..2E)=dst
  const int*   batch = (const int*)d_in[2];
  const float* W0 = (const float*)d_in[3];
  const float* aS0 = (const float*)d_in[4];
  const float* aD0 = (const float*)d_in[5];
  const float* b0 = (const float*)d_in[6];
  const float* W1 = (const float*)d_in[7];
  const float* aS1 = (const float*)d_in[8];
  const float* aD1 = (const float*)d_in[9];
  const float* b1 = (const float*)d_in[10];
  const float* W2 = (const float*)d_in[11];
  const float* aS2 = (const float*)d_in[12];
  const float* aD2 = (const float*)d_in[13];
  const float* b2 = (const float*)d_in[14];
  const float* fc1_w = (const float*)d_in[15];
  const float* fc1_b = (const float*)d_in[16];
  const float* fc2_w = (const float*)d_in[17];
  const float* fc2_b = (const float*)d_in[18];
  float* out = (float*)d_out;

  char* ws = (char*)d_ws;
  float* h   = (float*)ws;  ws += (size_t)N_NODES * HID * sizeof(float);
  float* xb  = (float*)ws;  ws += (size_t)N_NODES * HID * sizeof(float);
  float* as_ = (float*)ws;  ws += (size_t)N_NODES * sizeof(float);
  float* ad_ = (float*)ws;  ws += (size_t)N_NODES * sizeof(float);
  int* row_start = (int*)ws; ws += (size_t)(N_NODES + 1) * sizeof(int);
  int* cursor    = (int*)ws; ws += (size_t)N_NODES * sizeof(int);
  int* deg       = (int*)ws; ws += (size_t)N_NODES * sizeof(int);
  int* csr_src   = (int*)ws; ws += (size_t)ET * sizeof(int);

  const int* esrc = eidx;
  const int* edst = eidx + N_EDGES;

  // CSR build (edges identical for all 3 layers)
  k_init_deg<<<(N_NODES + 255) / 256, 256, 0, stream>>>(deg);
  k_hist<<<(N_EDGES + 255) / 256, 256, 0, stream>>>(edst, deg);
  k_scan<<<1, 1024, 0, stream>>>(deg, row_start, cursor);
  k_fill<<<(ET + 255) / 256, 256, 0, stream>>>(esrc, edst, cursor, csr_src);

  dim3 ggrid((N_NODES + TM - 1) / TM, HID / TN);
  int agg_grid = (N_NODES + 3) / 4;
  int zgrid = (2 * N_NODES + 255) / 256;    // as_ and ad_ are contiguous

  // layer 0 (din=7): non-atomic alpha write, no zeroing needed
  k_gemm_small<IN_CH, 32><<<(N_NODES + 31) / 32, 128, 0, stream>>>(x_in, W0, aS0, aD0, h, as_, ad_);
  k_agg<<<agg_grid, 256, 0, stream>>>(h, as_, ad_, row_start, csr_src, b0, xb);
  // layer 1
  k_zero<<<zgrid, 256, 0, stream>>>(as_, 2 * N_NODES);
  k_gemm128<<<ggrid, 256, 0, stream>>>(xb, W1, aS1, aD1, h, as_, ad_);
  k_agg<<<agg_grid, 256, 0, stream>>>(h, as_, ad_, row_start, csr_src, b1, xb);
  // layer 2
  k_zero<<<zgrid, 256, 0, stream>>>(as_, 2 * N_NODES);
  k_gemm128<<<ggrid, 256, 0, stream>>>(xb, W2, aS2, aD2, h, as_, ad_);
  k_agg<<<agg_grid, 256, 0, stream>>>(h, as_, ad_, row_start, csr_src, b2, xb);

  // head
  k_pool_mlp<<<N_GRAPHS, 128, 0, stream>>>(xb, batch, fc1_w, fc1_b, fc2_w, fc2_b, out);
}

// Round 6
// 541.110 us; speedup vs baseline: 1.3656x; 1.0535x over previous
//
#include <hip/hip_runtime.h>
#include <math.h>

#define N_NODES 50000
#define N_EDGES 800000
#define N_GRAPHS 512
#define IN_CH 7
#define HID 128
#define FC 128
#define ET (N_EDGES + N_NODES)   // real edges + self loops
#define NEG_SLOPE 0.2f

// ---------------- CSR build (once per call; edges identical across layers) ----------------

__global__ void k_init_deg(int* __restrict__ deg) {
  int i = blockIdx.x * blockDim.x + threadIdx.x;
  if (i < N_NODES) deg[i] = 1;  // self-loop occupies slot 0 of each row
}

// histogram AND capture each edge's rank within its dst (the atomic's return value,
// previously discarded) -> k_fill needs no atomics at all.
__global__ void k_hist(const int* __restrict__ dst, int* __restrict__ deg,
                       int* __restrict__ rank) {
  int i = blockIdx.x * blockDim.x + threadIdx.x;
  if (i < N_EDGES) rank[i] = atomicAdd(&deg[dst[i]], 1);   // rank >= 1 (slot 0 = self-loop)
}

// single-block hierarchical exclusive scan over N_NODES degrees
__global__ __launch_bounds__(1024) void k_scan(const int* __restrict__ deg,
                                               int* __restrict__ row_start) {
  __shared__ int wsum[16];
  __shared__ int s_carry;
  int tid = threadIdx.x;
  int lane = tid & 63, wid = tid >> 6;
  if (tid == 0) s_carry = 0;
  __syncthreads();
  for (int base = 0; base < N_NODES; base += 1024) {
    int i = base + tid;
    int v = (i < N_NODES) ? deg[i] : 0;
    int inc = v;
    #pragma unroll
    for (int off = 1; off < 64; off <<= 1) {
      int t = __shfl_up(inc, off, 64);
      if (lane >= off) inc += t;
    }
    if (lane == 63) wsum[wid] = inc;
    __syncthreads();
    if (wid == 0) {
      int wv = (lane < 16) ? wsum[lane] : 0;
      #pragma unroll
      for (int off = 1; off < 16; off <<= 1) {
        int t = __shfl_up(wv, off, 64);
        if (lane >= off) wv += t;
      }
      if (lane < 16) wsum[lane] = wv;   // inclusive wave-total scan
    }
    __syncthreads();
    int woff = (wid > 0) ? wsum[wid - 1] : 0;
    int incl = s_carry + woff + inc;
    int excl = incl - v;
    if (i < N_NODES) row_start[i] = excl;
    __syncthreads();                    // everyone done reading s_carry / wsum
    if (tid == 1023) s_carry += wsum[15];
    __syncthreads();
  }
  if (tid == 0) row_start[N_NODES] = s_carry;  // == ET
}

// atomic-free fill: pos = row_start[dst] + rank (row_start is a hot 200KB table)
__global__ void k_fill(const int* __restrict__ esrc, const int* __restrict__ edst,
                       const int* __restrict__ rank, const int* __restrict__ row_start,
                       int* __restrict__ csr_src) {
  int i = blockIdx.x * blockDim.x + threadIdx.x;
  if (i < ET) {
    if (i < N_EDGES) {
      int pos = row_start[edst[i]] + rank[i];
      __builtin_nontemporal_store(esrc[i], &csr_src[pos]);
    } else {
      int node = i - N_EDGES;
      __builtin_nontemporal_store(node, &csr_src[row_start[node]]);  // self loop slot 0
    }
  }
}

__global__ void k_zero(float* __restrict__ p, int n) {
  int i = blockIdx.x * blockDim.x + threadIdx.x;
  if (i < n) p[i] = 0.f;
}

// ---------------- layer-0 GEMM (din=7): h = x @ W ; as = h@a_src ; ad = h@a_dst ----------------

template<int DIN, int NPB>
__global__ __launch_bounds__(128) void k_gemm_small(const float* __restrict__ x,
                                                    const float* __restrict__ W,
                                                    const float* __restrict__ a_s,
                                                    const float* __restrict__ a_d,
                                                    float* __restrict__ h,
                                                    float* __restrict__ as_,
                                                    float* __restrict__ ad_) {
  __shared__ float Ws[DIN * HID];
  __shared__ float xs[DIN];
  __shared__ float red[4];
  int tid = threadIdx.x;
  for (int i = tid; i < DIN * HID; i += 128) Ws[i] = W[i];
  float asf = a_s[tid], adf = a_d[tid];
  int node0 = blockIdx.x * NPB;
  for (int nn = 0; nn < NPB; ++nn) {
    int node = node0 + nn;
    if (node >= N_NODES) break;          // uniform across block
    __syncthreads();                     // covers Ws staging (first iter) + xs/red reuse
    if (tid < DIN) xs[tid] = x[(size_t)node * DIN + tid];
    __syncthreads();
    float acc = 0.f;
    #pragma unroll
    for (int k = 0; k < DIN; ++k) acc = fmaf(xs[k], Ws[k * HID + tid], acc);
    h[(size_t)node * HID + tid] = acc;
    float vs = acc * asf, vd = acc * adf;
    #pragma unroll
    for (int off = 32; off >= 1; off >>= 1) {
      vs += __shfl_xor(vs, off, 64);
      vd += __shfl_xor(vd, off, 64);
    }
    int lane = tid & 63, wid = tid >> 6;
    if (lane == 0) { red[wid * 2] = vs; red[wid * 2 + 1] = vd; }
    __syncthreads();
    if (tid == 0)      as_[node] = red[0] + red[2];
    else if (tid == 1) ad_[node] = red[1] + red[3];
  }
}

// ---------------- hidden GEMM (din=128): LDS-tiled, 4x4 register micro-tile ----------------

#define TM 64
#define TN 64

__global__ __launch_bounds__(256, 2) void k_gemm128(const float* __restrict__ x,
                                                    const float* __restrict__ W,
                                                    const float* __restrict__ a_s,
                                                    const float* __restrict__ a_d,
                                                    float* __restrict__ h,
                                                    float* __restrict__ as_,
                                                    float* __restrict__ ad_) {
  __shared__ float xT[HID][TM + 4];     // 128 x 68 x 4B = 34.8KB
  __shared__ float Wl[HID][TN + 4];     // 34.8KB
  int tid = threadIdx.x;
  int node0 = blockIdx.x * TM;
  int col0  = blockIdx.y * TN;

  // stage x tile transposed: 64 rows x 128 k (coalesced float4 reads)
  {
    const float4* xg = (const float4*)x;
    #pragma unroll
    for (int it = 0; it < (TM * 32) / 256; ++it) {
      int idx = tid + it * 256;
      int r = idx >> 5, k4 = idx & 31;
      int node = node0 + r;
      float4 v = make_float4(0.f, 0.f, 0.f, 0.f);
      if (node < N_NODES) v = xg[(size_t)node * 32 + k4];
      xT[4 * k4 + 0][r] = v.x;
      xT[4 * k4 + 1][r] = v.y;
      xT[4 * k4 + 2][r] = v.z;
      xT[4 * k4 + 3][r] = v.w;
    }
  }
  // stage W slice: 128 k x 64 cols
  {
    const float4* wg = (const float4*)W;
    #pragma unroll
    for (int it = 0; it < (HID * (TN / 4)) / 256; ++it) {
      int idx = tid + it * 256;
      int k = idx >> 4, c4 = idx & 15;
      float4 v = wg[(size_t)k * 32 + (col0 >> 2) + c4];
      *(float4*)&Wl[k][4 * c4] = v;
    }
  }
  __syncthreads();

  int cg = tid & 15;        // col group: cols col0 + 4*cg .. +3
  int nr = tid >> 4;        // node group: nodes node0 + 4*nr .. +3
  float acc00 = 0.f, acc01 = 0.f, acc02 = 0.f, acc03 = 0.f;
  float acc10 = 0.f, acc11 = 0.f, acc12 = 0.f, acc13 = 0.f;
  float acc20 = 0.f, acc21 = 0.f, acc22 = 0.f, acc23 = 0.f;
  float acc30 = 0.f, acc31 = 0.f, acc32 = 0.f, acc33 = 0.f;

  #pragma unroll 8
  for (int k = 0; k < HID; ++k) {
    float4 xv = *(const float4*)&xT[k][nr * 4];
    float4 wv = *(const float4*)&Wl[k][cg * 4];
    acc00 = fmaf(xv.x, wv.x, acc00); acc01 = fmaf(xv.x, wv.y, acc01);
    acc02 = fmaf(xv.x, wv.z, acc02); acc03 = fmaf(xv.x, wv.w, acc03);
    acc10 = fmaf(xv.y, wv.x, acc10); acc11 = fmaf(xv.y, wv.y, acc11);
    acc12 = fmaf(xv.y, wv.z, acc12); acc13 = fmaf(xv.y, wv.w, acc13);
    acc20 = fmaf(xv.z, wv.x, acc20); acc21 = fmaf(xv.z, wv.y, acc21);
    acc22 = fmaf(xv.z, wv.z, acc22); acc23 = fmaf(xv.z, wv.w, acc23);
    acc30 = fmaf(xv.w, wv.x, acc30); acc31 = fmaf(xv.w, wv.y, acc31);
    acc32 = fmaf(xv.w, wv.z, acc32); acc33 = fmaf(xv.w, wv.w, acc33);
  }

  // epilogue: store h + fused alpha partials
  float as0 = a_s[col0 + 4 * cg + 0], as1 = a_s[col0 + 4 * cg + 1];
  float as2 = a_s[col0 + 4 * cg + 2], as3 = a_s[col0 + 4 * cg + 3];
  float ad0 = a_d[col0 + 4 * cg + 0], ad1 = a_d[col0 + 4 * cg + 1];
  float ad2 = a_d[col0 + 4 * cg + 2], ad3 = a_d[col0 + 4 * cg + 3];

  #pragma unroll
  for (int i = 0; i < 4; ++i) {
    float r0 = (i == 0) ? acc00 : (i == 1) ? acc10 : (i == 2) ? acc20 : acc30;
    float r1 = (i == 0) ? acc01 : (i == 1) ? acc11 : (i == 2) ? acc21 : acc31;
    float r2 = (i == 0) ? acc02 : (i == 1) ? acc12 : (i == 2) ? acc22 : acc32;
    float r3 = (i == 0) ? acc03 : (i == 1) ? acc13 : (i == 2) ? acc23 : acc33;
    int node = node0 + nr * 4 + i;
    float ps = fmaf(r0, as0, fmaf(r1, as1, fmaf(r2, as2, r3 * as3)));
    float pd = fmaf(r0, ad0, fmaf(r1, ad1, fmaf(r2, ad2, r3 * ad3)));
    #pragma unroll
    for (int off = 1; off < 16; off <<= 1) {
      ps += __shfl_xor(ps, off, 16);
      pd += __shfl_xor(pd, off, 16);
    }
    if (node < N_NODES) {
      float4 hv; hv.x = r0; hv.y = r1; hv.z = r2; hv.w = r3;
      *(float4*)&h[(size_t)node * HID + col0 + 4 * cg] = hv;
      if (cg == 0) {
        atomicAdd(&as_[node], ps);
        atomicAdd(&ad_[node], pd);
      }
    }
  }
}

// ---------------- aggregation: wave per node; half-wave x float4 gathers, 8 rows in flight ----------------

__global__ __launch_bounds__(256) void k_agg(const float* __restrict__ h,
                                             const float* __restrict__ as_,
                                             const float* __restrict__ ad_,
                                             const int* __restrict__ row_start,
                                             const int* __restrict__ csr_src,
                                             const float* __restrict__ b,
                                             float* __restrict__ out) {
  int wid = threadIdx.x >> 6, lane = threadIdx.x & 63;
  int node = blockIdx.x * 4 + wid;
  if (node >= N_NODES) return;
  int beg = row_start[node], end = row_start[node + 1];
  int n = end - beg;                     // >= 1 (self-loop)
  float adn = ad_[node];
  int sub = lane & 31, half = lane >> 5;
  const float4* h4 = (const float4*)h;
  float4 accA = make_float4(0.f, 0.f, 0.f, 0.f);
  float4 accB = make_float4(0.f, 0.f, 0.f, 0.f);
  float inv;

  if (n <= 64) {
    // --- softmax fully lane-parallel (one load round-trip) ---
    int sc_l = csr_src[beg + (lane < n ? lane : n - 1)];
    float e = as_[sc_l] + adn;
    e = e > 0.f ? e : NEG_SLOPE * e;
    float m = (lane < n) ? e : -INFINITY;
    #pragma unroll
    for (int off = 32; off >= 1; off >>= 1) m = fmaxf(m, __shfl_xor(m, off, 64));
    float we = (lane < n) ? __expf(e - m) : 0.f;
    float s = we;
    #pragma unroll
    for (int off = 32; off >= 1; off >>= 1) s += __shfl_xor(s, off, 64);
    inv = 1.f / (s + 1e-16f);

    // --- gather: half-wave per row (32 x float4 = 512B), 8 edges (rows) in flight ---
    int j = 0;
    for (; j + 8 <= n; j += 8) {
      int e0 = j + half, e1 = j + 2 + half, e2 = j + 4 + half, e3 = j + 6 + half;
      int s0 = __shfl(sc_l, e0, 64);
      int s1 = __shfl(sc_l, e1, 64);
      int s2 = __shfl(sc_l, e2, 64);
      int s3 = __shfl(sc_l, e3, 64);
      float w0 = __shfl(we, e0, 64);
      float w1 = __shfl(we, e1, 64);
      float w2 = __shfl(we, e2, 64);
      float w3 = __shfl(we, e3, 64);
      float4 v0 = h4[(size_t)s0 * 32 + sub];
      float4 v1 = h4[(size_t)s1 * 32 + sub];
      float4 v2 = h4[(size_t)s2 * 32 + sub];
      float4 v3 = h4[(size_t)s3 * 32 + sub];
      accA.x = fmaf(w0, v0.x, accA.x); accA.y = fmaf(w0, v0.y, accA.y);
      accA.z = fmaf(w0, v0.z, accA.z); accA.w = fmaf(w0, v0.w, accA.w);
      accB.x = fmaf(w1, v1.x, accB.x); accB.y = fmaf(w1, v1.y, accB.y);
      accB.z = fmaf(w1, v1.z, accB.z); accB.w = fmaf(w1, v1.w, accB.w);
      accA.x = fmaf(w2, v2.x, accA.x); accA.y = fmaf(w2, v2.y, accA.y);
      accA.z = fmaf(w2, v2.z, accA.z); accA.w = fmaf(w2, v2.w, accA.w);
      accB.x = fmaf(w3, v3.x, accB.x); accB.y = fmaf(w3, v3.y, accB.y);
      accB.z = fmaf(w3, v3.z, accB.z); accB.w = fmaf(w3, v3.w, accB.w);
    }
    for (; j < n; j += 2) {
      int ej = j + half;                 // ej <= n; we[ej]=0 if ej==n (clamped sc is valid)
      int sj = __shfl(sc_l, ej, 64);
      float wj = (ej < n) ? __shfl(we, ej, 64) : 0.f;
      float4 vj = h4[(size_t)sj * 32 + sub];
      accA.x = fmaf(wj, vj.x, accA.x); accA.y = fmaf(wj, vj.y, accA.y);
      accA.z = fmaf(wj, vj.z, accA.z); accA.w = fmaf(wj, vj.w, accA.w);
    }
  } else {
    // --- generic path (deg > 64): two-pass, half-wave float4 gathers ---
    float m = -INFINITY;
    for (int i = beg + lane; i < end; i += 64) {
      float e = as_[csr_src[i]] + adn;
      e = e > 0.f ? e : NEG_SLOPE * e;
      m = fmaxf(m, e);
    }
    #pragma unroll
    for (int off = 32; off >= 1; off >>= 1) m = fmaxf(m, __shfl_xor(m, off, 64));
    float s = 0.f;
    for (int i = beg + half; i < end; i += 2) {
      int sc = csr_src[i];
      float e = as_[sc] + adn;
      e = e > 0.f ? e : NEG_SLOPE * e;
      float w = __expf(e - m);
      if (sub == 0) s += w;              // count each edge once per half
      float4 hv = h4[(size_t)sc * 32 + sub];
      accA.x = fmaf(w, hv.x, accA.x); accA.y = fmaf(w, hv.y, accA.y);
      accA.z = fmaf(w, hv.z, accA.z); accA.w = fmaf(w, hv.w, accA.w);
    }
    #pragma unroll
    for (int off = 32; off >= 1; off >>= 1) s += __shfl_xor(s, off, 64);
    inv = 1.f / (s + 1e-16f);
  }

  // combine the two halves (same features live in lane and lane^32)
  accA.x += accB.x; accA.y += accB.y; accA.z += accB.z; accA.w += accB.w;
  accA.x += __shfl_xor(accA.x, 32, 64);
  accA.y += __shfl_xor(accA.y, 32, 64);
  accA.z += __shfl_xor(accA.z, 32, 64);
  accA.w += __shfl_xor(accA.w, 32, 64);

  if (half == 0) {
    float4 bv = ((const float4*)b)[sub];
    float v0 = accA.x * inv + bv.x;
    float v1 = accA.y * inv + bv.y;
    float v2 = accA.z * inv + bv.z;
    float v3 = accA.w * inv + bv.w;
    v0 = v0 > 0.f ? v0 : expm1f(v0);     // ELU
    v1 = v1 > 0.f ? v1 : expm1f(v1);
    v2 = v2 > 0.f ? v2 : expm1f(v2);
    v3 = v3 > 0.f ? v3 : expm1f(v3);
    float4 ov; ov.x = v0; ov.y = v1; ov.z = v2; ov.w = v3;
    ((float4*)out)[(size_t)node * 32 + sub] = ov;
  }
}

// ---------------- mean-pool (sorted batch, binary search) + fc1/relu + fc2 + log_softmax ----------------

__global__ __launch_bounds__(128) void k_pool_mlp(const float* __restrict__ x,
                                                  const int* __restrict__ batch,
                                                  const float* __restrict__ fc1_w,
                                                  const float* __restrict__ fc1_b,
                                                  const float* __restrict__ fc2_w,
                                                  const float* __restrict__ fc2_b,
                                                  float* __restrict__ out) {
  __shared__ float g[HID];
  __shared__ float h1[HID];
  __shared__ float lgs[2];
  int gid = blockIdx.x, tid = threadIdx.x;
  int a = 0, bnd = N_NODES;
  while (a < bnd) { int mid = (a + bnd) >> 1; if (batch[mid] < gid) a = mid + 1; else bnd = mid; }
  int lo = a;
  bnd = N_NODES;
  while (a < bnd) { int mid = (a + bnd) >> 1; if (batch[mid] < gid + 1) a = mid + 1; else bnd = mid; }
  int hi = a;
  float acc = 0.f;
  for (int n = lo; n < hi; ++n) acc += x[(size_t)n * HID + tid];
  float cnt = (float)(hi - lo);
  g[tid] = acc / fmaxf(cnt, 1.f);
  __syncthreads();
  float a1 = fc1_b[tid];
  #pragma unroll 8
  for (int k = 0; k < HID; ++k) a1 = fmaf(g[k], fc1_w[k * FC + tid], a1);
  a1 = fmaxf(a1, 0.f);
  h1[tid] = a1;
  __syncthreads();
  int lane = tid & 63, w = tid >> 6;   // wave w computes logit w (2 classes)
  float p = h1[lane] * fc2_w[lane * 2 + w] + h1[64 + lane] * fc2_w[(64 + lane) * 2 + w];
  #pragma unroll
  for (int off = 32; off >= 1; off >>= 1) p += __shfl_xor(p, off, 64);
  if (lane == 0) lgs[w] = p + fc2_b[w];
  __syncthreads();
  if (tid == 0) {
    float l0 = lgs[0], l1 = lgs[1];
    float mx = fmaxf(l0, l1);
    float lse = mx + logf(expf(l0 - mx) + expf(l1 - mx));
    out[gid * 2 + 0] = l0 - lse;
    out[gid * 2 + 1] = l1 - lse;
  }
}

// ---------------- launch ----------------

extern "C" void kernel_launch(void* const* d_in, const int* in_sizes, int n_in,
                              void* d_out, int out_size, void* d_ws, size_t ws_size,
                              hipStream_t stream) {
  const float* x_in  = (const float*)d_in[0];
  const int*   eidx  = (const int*)d_in[1];   // [2, N_EDGES]: [0..E)=src, [E..2E)=dst
  const int*   batch = (const int*)d_in[2];
  const float* W0 = (const float*)d_in[3];
  const float* aS0 = (const float*)d_in[4];
  const float* aD0 = (const float*)d_in[5];
  const float* b0 = (const float*)d_in[6];
  const float* W1 = (const float*)d_in[7];
  const float* aS1 = (const float*)d_in[8];
  const float* aD1 = (const float*)d_in[9];
  const float* b1 = (const float*)d_in[10];
  const float* W2 = (const float*)d_in[11];
  const float* aS2 = (const float*)d_in[12];
  const float* aD2 = (const float*)d_in[13];
  const float* b2 = (const float*)d_in[14];
  const float* fc1_w = (const float*)d_in[15];
  const float* fc1_b = (const float*)d_in[16];
  const float* fc2_w = (const float*)d_in[17];
  const float* fc2_b = (const float*)d_in[18];
  float* out = (float*)d_out;

  char* ws = (char*)d_ws;
  float* h   = (float*)ws;  ws += (size_t)N_NODES * HID * sizeof(float);
  float* xb  = (float*)ws;  ws += (size_t)N_NODES * HID * sizeof(float);
  float* as_ = (float*)ws;  ws += (size_t)N_NODES * sizeof(float);
  float* ad_ = (float*)ws;  ws += (size_t)N_NODES * sizeof(float);
  int* row_start = (int*)ws; ws += (size_t)(N_NODES + 1) * sizeof(int);
  int* deg       = (int*)ws; ws += (size_t)N_NODES * sizeof(int);
  int* rank      = (int*)ws; ws += (size_t)N_EDGES * sizeof(int);
  int* csr_src   = (int*)ws; ws += (size_t)ET * sizeof(int);

  const int* esrc = eidx;
  const int* edst = eidx + N_EDGES;

  // CSR build (edges identical for all 3 layers)
  k_init_deg<<<(N_NODES + 255) / 256, 256, 0, stream>>>(deg);
  k_hist<<<(N_EDGES + 255) / 256, 256, 0, stream>>>(edst, deg, rank);
  k_scan<<<1, 1024, 0, stream>>>(deg, row_start);
  k_fill<<<(ET + 255) / 256, 256, 0, stream>>>(esrc, edst, rank, row_start, csr_src);

  dim3 ggrid((N_NODES + TM - 1) / TM, HID / TN);
  int agg_grid = (N_NODES + 3) / 4;
  int zgrid = (2 * N_NODES + 255) / 256;    // as_ and ad_ are contiguous

  // layer 0 (din=7): non-atomic alpha write, no zeroing needed
  k_gemm_small<IN_CH, 32><<<(N_NODES + 31) / 32, 128, 0, stream>>>(x_in, W0, aS0, aD0, h, as_, ad_);
  k_agg<<<agg_grid, 256, 0, stream>>>(h, as_, ad_, row_start, csr_src, b0, xb);
  // layer 1
  k_zero<<<zgrid, 256, 0, stream>>>(as_, 2 * N_NODES);
  k_gemm128<<<ggrid, 256, 0, stream>>>(xb, W1, aS1, aD1, h, as_, ad_);
  k_agg<<<agg_grid, 256, 0, stream>>>(h, as_, ad_, row_start, csr_src, b1, xb);
  // layer 2
  k_zero<<<zgrid, 256, 0, stream>>>(as_, 2 * N_NODES);
  k_gemm128<<<ggrid, 256, 0, stream>>>(xb, W2, aS2, aD2, h, as_, ad_);
  k_agg<<<agg_grid, 256, 0, stream>>>(h, as_, ad_, row_start, csr_src, b2, xb);

  // head
  k_pool_mlp<<<N_GRAPHS, 128, 0, stream>>>(xb, batch, fc1_w, fc1_b, fc2_w, fc2_b, out);
}